// Round 10
// baseline (1875.962 us; speedup 1.0000x reference)
//
#include <hip/hip_runtime.h>
#include <hip/hip_bf16.h>
#include <stdint.h>

typedef int int4v __attribute__((ext_vector_type(4)));
typedef int int16v __attribute__((ext_vector_type(16)));
typedef float float4v __attribute__((ext_vector_type(4)));

#define KDIM 4096
#define TDIM 11008
#define BDIM 4096
#define GDIM 32

// ---------- kernel 0: per-column weight scale  dwt[t] = max_g s*max(z,15-z) / 127 ----------
__global__ __launch_bounds__(256) void dwt_k(const float* __restrict__ scales,
                                             const float* __restrict__ zeros,
                                             float* __restrict__ dwt,
                                             float* __restrict__ dwtinv) {
  int t = blockIdx.x * 256 + threadIdx.x;  // 43*256 = 11008 exact
  float m = 1e-20f;
#pragma unroll 4
  for (int g = 0; g < GDIM; ++g) {
    float s = scales[(size_t)g * TDIM + t];
    float z = zeros[(size_t)g * TDIM + t];
    m = fmaxf(m, s * fmaxf(z, 15.0f - z));
  }
  dwt[t] = m * (1.0f / 127.0f);
  dwtinv[t] = 127.0f / m;
}

// ---------- kernel 1: fused prep — blocks [0,5504): dequant int4->int8 wq[T][K];
//                      blocks [5504,9600): per-row x quant ----------
__global__ __launch_bounds__(256) void prep_k(const unsigned* __restrict__ qw,
                                              const float* __restrict__ scales,
                                              const float* __restrict__ zeros,
                                              const float* __restrict__ dwtinv,
                                              const float* __restrict__ x,
                                              char* __restrict__ wq,
                                              char* __restrict__ xq,
                                              float* __restrict__ dxr) {
  if (blockIdx.x < 5504) {
    int idx = blockIdx.x * 256 + threadIdx.x;  // 128*TDIM exact
    int rb = idx / TDIM;
    int t = idx - rb * TDIM;
    int r0 = rb * 4, g = rb >> 2;
    float s = scales[(size_t)g * TDIM + t];
    float z = zeros[(size_t)g * TDIM + t];
    float inv = dwtinv[t];
    float si = s * inv;
    float zi = -z * si;
    int w[8];
#pragma unroll
    for (int c = 0; c < 4; ++c) {
      unsigned q = qw[(size_t)(r0 + c) * TDIM + t];
      unsigned lo = 0, hi = 0;
#pragma unroll
      for (int i = 0; i < 4; ++i) {
        int iv = (int)rintf(fmaf((float)((q >> (4 * i)) & 0xFu), si, zi));
        lo |= (unsigned)(iv & 0xFF) << (8 * i);
      }
#pragma unroll
      for (int i = 4; i < 8; ++i) {
        int iv = (int)rintf(fmaf((float)((q >> (4 * i)) & 0xFu), si, zi));
        hi |= (unsigned)(iv & 0xFF) << (8 * (i - 4));
      }
      w[2 * c] = (int)lo;
      w[2 * c + 1] = (int)hi;
    }
    int4v v0 = {w[0], w[1], w[2], w[3]};
    int4v v1 = {w[4], w[5], w[6], w[7]};
    char* dst = wq + (size_t)t * KDIM + rb * 32;
    *(int4v*)dst = v0;
    *(int4v*)(dst + 16) = v1;
  } else {
    const int b = blockIdx.x - 5504;  // 4096 rows
    const int tid = threadIdx.x;
    const float* row = x + (size_t)b * KDIM;
    float4v v[4];
    float m = 0.0f;
#pragma unroll
    for (int j = 0; j < 4; ++j) {
      v[j] = *(const float4v*)(row + (tid + 256 * j) * 4);
#pragma unroll
      for (int i = 0; i < 4; ++i) m = fmaxf(m, fabsf(v[j][i]));
    }
#pragma unroll
    for (int off = 1; off < 64; off <<= 1) m = fmaxf(m, __shfl_xor(m, off));
    __shared__ float sm[4];
    if ((tid & 63) == 0) sm[tid >> 6] = m;
    __syncthreads();
    float rm = fmaxf(fmaxf(sm[0], sm[1]), fmaxf(sm[2], sm[3]));
    rm = fmaxf(rm, 1e-20f);
    if (tid == 0) dxr[b] = rm * (1.0f / 127.0f);
    float inv = 127.0f / rm;
#pragma unroll
    for (int j = 0; j < 4; ++j) {
      unsigned w = 0;
#pragma unroll
      for (int i = 0; i < 4; ++i) {
        int iv = (int)rintf(v[j][i] * inv);
        w |= (unsigned)(iv & 0xFF) << (8 * i);
      }
      *(unsigned*)(xq + (size_t)b * KDIM + (tid + 256 * j) * 4) = w;
    }
  }
}

// ---------- kernel 2: 128x256 i8 GEMM, 4 waves, 48KB LDS -> 3 blocks/CU ----------
// TILEQ sync structure identical to R9 (empirically race-validated x3 rounds):
// reads ks0(6)+ks1(6) -> BARR -> lgkm6 -> MFMA ks0 -> lgkm0 -> stage(6) -> MFMA ks1
// -> vmcnt(6) -> BARR. vmcnt never below 6 in flight; stage write window = post-BARR.
static __device__ __forceinline__ void gload16(const void* g, void* l) {
  __builtin_amdgcn_global_load_lds(
      (const __attribute__((address_space(1))) unsigned*)g,
      (__attribute__((address_space(3))) unsigned*)l, 16, 0, 0);
}

#define BARR() __builtin_amdgcn_s_barrier()
#define LGKM0() asm volatile("s_waitcnt lgkmcnt(0)" ::: "memory")
#define LGKM6() asm volatile("s_waitcnt lgkmcnt(6)" ::: "memory")
#define VMC6() asm volatile("s_waitcnt vmcnt(6)" ::: "memory")
#define SB0() __builtin_amdgcn_sched_barrier(0)

__global__ __launch_bounds__(256, 3) void gemmq2_k(const char* __restrict__ xq,
                                                   const char* __restrict__ wq,
                                                   const float* __restrict__ dxr,
                                                   const float* __restrict__ dwt,
                                                   const float* __restrict__ bias,
                                                   float* __restrict__ out) {
  __shared__ char sA[2 * 128 * 64];  // 16 KiB: [buf][128 rows][64K] i8
  __shared__ char sB[2 * 256 * 64];  // 32 KiB: [buf][256 rows][64K] i8
  const int tid = threadIdx.x;
  const int lane = tid & 63;
  const int wn = tid >> 6;  // 4 waves, each owns 64 output cols; all share 128 rows

  // XCD swizzle: nwg = 32*43 = 1376 = 8*172
  const int bid = blockIdx.x;
  const int swzb = (bid & 7) * 172 + (bid >> 3);
  const int mb = swzb / 43, nb = swzb % 43;
  const int m0 = mb * 128, n0 = nb * 256;

  // staging: chunk ci covers row ci>>2, phys pos ci&3; A: ci in {tid, tid+256},
  // B: ci in {tid, tid+256, tid+512, tid+768}. +64-row offsets preserve both XOR
  // terms ((row&3), ((row>>2)&3)) -> same source kb for all of a thread's chunks.
  const int srow = tid >> 2;  // 0..63
  const int spc = tid & 3;
  const int skb = spc ^ (srow & 3) ^ ((srow >> 2) & 3);
  const char* gA = xq + (size_t)(m0 + srow) * KDIM + skb * 16;
  const char* gB = wq + (size_t)(n0 + srow) * KDIM + skb * 16;

  auto stA = [&](int b, int kt) {
    gload16(gA + kt * 64, sA + b * 8192 + tid * 16);
    gload16(gA + (size_t)64 * KDIM + kt * 64, sA + b * 8192 + tid * 16 + 4096);
  };
  auto stB = [&](int b, int kt) {
#pragma unroll
    for (int j = 0; j < 4; ++j)
      gload16(gB + (size_t)(64 * j) * KDIM + kt * 64, sB + b * 16384 + tid * 16 + j * 4096);
  };

  // read addressing: phys chunk = (ks*2 + hi5') ... 4 chunks of 16B per 64B row:
  // phys = (hi5 ^ rowswz) with ks flipping bit1
  const int l31 = lane & 31, hi5 = lane >> 5;
  const int rsw = (l31 & 3) ^ ((l31 >> 2) & 3);
  const int pc0 = (hi5 ^ rsw) * 16;
  const int pc1 = ((hi5 ^ rsw) ^ 2) * 16;
  const char* aRd = sA + l31 * 64;                // A rows l31 + fi*32 (fi*32 keeps XOR terms)
  const char* bRd = sB + (wn * 64 + l31) * 64;    // B rows wn*64 + fj*32 + l31

  int16v acc[4][2];
#pragma unroll
  for (int i = 0; i < 4; ++i)
#pragma unroll
    for (int j = 0; j < 2; ++j) acc[i][j] = (int16v)(0);

#define TILEQ(BUF, TT)                                                        \
  {                                                                           \
    const char* ap = aRd + (BUF) * 8192;                                      \
    const char* bp = bRd + (BUF) * 16384;                                     \
    int4v av[4][2], bv[2][2];                                                 \
    _Pragma("unroll") for (int fi = 0; fi < 4; ++fi)                          \
      av[fi][0] = *(const int4v*)(ap + fi * 2048 + pc0);                      \
    _Pragma("unroll") for (int fj = 0; fj < 2; ++fj)                          \
      bv[fj][0] = *(const int4v*)(bp + fj * 2048 + pc0);                      \
    _Pragma("unroll") for (int fi = 0; fi < 4; ++fi)                          \
      av[fi][1] = *(const int4v*)(ap + fi * 2048 + pc1);                      \
    _Pragma("unroll") for (int fj = 0; fj < 2; ++fj)                          \
      bv[fj][1] = *(const int4v*)(bp + fj * 2048 + pc1);                      \
    SB0();                                                                    \
    BARR();                                                                   \
    LGKM6(); SB0();                                                           \
    __builtin_amdgcn_s_setprio(1);                                            \
    _Pragma("unroll") for (int fi = 0; fi < 4; ++fi)                          \
      _Pragma("unroll") for (int fj = 0; fj < 2; ++fj)                        \
        acc[fi][fj] = __builtin_amdgcn_mfma_i32_32x32x32_i8(av[fi][0], bv[fj][0], acc[fi][fj], 0, 0, 0); \
    __builtin_amdgcn_s_setprio(0);                                            \
    LGKM0(); SB0();                                                           \
    const int kn = ((TT) + 2) & 63;                                           \
    stA(BUF, kn); stB(BUF, kn);                                               \
    SB0();                                                                    \
    __builtin_amdgcn_s_setprio(1);                                            \
    _Pragma("unroll") for (int fi = 0; fi < 4; ++fi)                          \
      _Pragma("unroll") for (int fj = 0; fj < 2; ++fj)                        \
        acc[fi][fj] = __builtin_amdgcn_mfma_i32_32x32x32_i8(av[fi][1], bv[fj][1], acc[fi][fj], 0, 0, 0); \
    __builtin_amdgcn_s_setprio(0);                                            \
    VMC6(); BARR();                                                           \
  }

  // prologue: stage tiles 0,1 (12 loads); vmcnt(6) -> tile0 landed
  stA(0, 0); stB(0, 0);
  stA(1, 1); stB(1, 1);
  VMC6();
  BARR();

  for (int u = 0; u < 32; ++u) {
    TILEQ(0, 2 * u);
    TILEQ(1, 2 * u + 1);
  }

  // epilogue: C layout (32x32): col = lane&31, row = (e&3) + 8*(e>>2) + 4*(lane>>5)
  const int colb = n0 + wn * 64 + l31;
  const int rowb = m0 + 4 * hi5;
#pragma unroll
  for (int fi = 0; fi < 4; ++fi) {
#pragma unroll
    for (int fj = 0; fj < 2; ++fj) {
      const int col = colb + fj * 32;
      const float dw = dwt[col];
      const float bs = bias[col];
      int16v c = acc[fi][fj];
#pragma unroll
      for (int e = 0; e < 16; ++e) {
        const int row = rowb + fi * 32 + (e & 3) + 8 * (e >> 2);
        out[(size_t)row * TDIM + col] = (float)c[e] * dw * dxr[row] + bs;
      }
    }
  }
}

extern "C" void kernel_launch(void* const* d_in, const int* in_sizes, int n_in,
                              void* d_out, int out_size, void* d_ws, size_t ws_size,
                              hipStream_t stream) {
  const float* x = (const float*)d_in[0];
  const unsigned* qw = (const unsigned*)d_in[1];
  const float* scales = (const float*)d_in[2];
  const float* zeros = (const float*)d_in[3];
  const float* bias = (const float*)d_in[4];
  float* out = (float*)d_out;

  char* ws = (char*)d_ws;
  char* wq = ws;                                   // [TDIM][KDIM] i8, 45.1MB
  char* xq = ws + (size_t)TDIM * KDIM;             // [BDIM][KDIM] i8, 16.8MB
  float* dwt = (float*)(ws + (size_t)TDIM * KDIM + (size_t)BDIM * KDIM);
  float* dwtinv = dwt + TDIM;
  float* dxr = dwtinv + TDIM;

  dwt_k<<<43, 256, 0, stream>>>(scales, zeros, dwt, dwtinv);
  prep_k<<<9600, 256, 0, stream>>>(qw, scales, zeros, dwtinv, x, wq, xq, dxr);
  gemmq2_k<<<1376, 256, 0, stream>>>(xq, wq, dxr, dwt, bias, out);
}

// Round 11
// 287.075 us; speedup vs baseline: 6.5347x; 6.5347x over previous
//
#include <hip/hip_runtime.h>
#include <hip/hip_bf16.h>
#include <stdint.h>

typedef int int4v __attribute__((ext_vector_type(4)));
typedef int int16v __attribute__((ext_vector_type(16)));
typedef float float4v __attribute__((ext_vector_type(4)));

#define KDIM 4096
#define TDIM 11008
#define BDIM 4096
#define GDIM 32

// ---------- kernel 0: per-column weight scale  dwt[t] = max_g s*max(z,15-z) / 127 ----------
__global__ __launch_bounds__(256) void dwt_k(const float* __restrict__ scales,
                                             const float* __restrict__ zeros,
                                             float* __restrict__ dwt,
                                             float* __restrict__ dwtinv) {
  int t = blockIdx.x * 256 + threadIdx.x;  // 43*256 = 11008 exact
  float m = 1e-20f;
#pragma unroll 4
  for (int g = 0; g < GDIM; ++g) {
    float s = scales[(size_t)g * TDIM + t];
    float z = zeros[(size_t)g * TDIM + t];
    m = fmaxf(m, s * fmaxf(z, 15.0f - z));
  }
  dwt[t] = m * (1.0f / 127.0f);
  dwtinv[t] = 127.0f / m;
}

// ---------- kernel 1: fused prep — blocks [0,5504): dequant int4->int8 wq[T][K];
//                      blocks [5504,9600): per-row x quant ----------
__global__ __launch_bounds__(256) void prep_k(const unsigned* __restrict__ qw,
                                              const float* __restrict__ scales,
                                              const float* __restrict__ zeros,
                                              const float* __restrict__ dwtinv,
                                              const float* __restrict__ x,
                                              char* __restrict__ wq,
                                              char* __restrict__ xq,
                                              float* __restrict__ dxr) {
  if (blockIdx.x < 5504) {
    int idx = blockIdx.x * 256 + threadIdx.x;  // 128*TDIM exact
    int rb = idx / TDIM;
    int t = idx - rb * TDIM;
    int r0 = rb * 4, g = rb >> 2;
    float s = scales[(size_t)g * TDIM + t];
    float z = zeros[(size_t)g * TDIM + t];
    float inv = dwtinv[t];
    float si = s * inv;
    float zi = -z * si;
    int w[8];
#pragma unroll
    for (int c = 0; c < 4; ++c) {
      unsigned q = qw[(size_t)(r0 + c) * TDIM + t];
      unsigned lo = 0, hi = 0;
#pragma unroll
      for (int i = 0; i < 4; ++i) {
        int iv = (int)rintf(fmaf((float)((q >> (4 * i)) & 0xFu), si, zi));
        lo |= (unsigned)(iv & 0xFF) << (8 * i);
      }
#pragma unroll
      for (int i = 4; i < 8; ++i) {
        int iv = (int)rintf(fmaf((float)((q >> (4 * i)) & 0xFu), si, zi));
        hi |= (unsigned)(iv & 0xFF) << (8 * (i - 4));
      }
      w[2 * c] = (int)lo;
      w[2 * c + 1] = (int)hi;
    }
    int4v v0 = {w[0], w[1], w[2], w[3]};
    int4v v1 = {w[4], w[5], w[6], w[7]};
    char* dst = wq + (size_t)t * KDIM + rb * 32;
    *(int4v*)dst = v0;
    *(int4v*)(dst + 16) = v1;
  } else {
    const int b = blockIdx.x - 5504;  // 4096 rows
    const int tid = threadIdx.x;
    const float* row = x + (size_t)b * KDIM;
    float4v v[4];
    float m = 0.0f;
#pragma unroll
    for (int j = 0; j < 4; ++j) {
      v[j] = *(const float4v*)(row + (tid + 256 * j) * 4);
#pragma unroll
      for (int i = 0; i < 4; ++i) m = fmaxf(m, fabsf(v[j][i]));
    }
#pragma unroll
    for (int off = 1; off < 64; off <<= 1) m = fmaxf(m, __shfl_xor(m, off));
    __shared__ float sm[4];
    if ((tid & 63) == 0) sm[tid >> 6] = m;
    __syncthreads();
    float rm = fmaxf(fmaxf(sm[0], sm[1]), fmaxf(sm[2], sm[3]));
    rm = fmaxf(rm, 1e-20f);
    if (tid == 0) dxr[b] = rm * (1.0f / 127.0f);
    float inv = 127.0f / rm;
#pragma unroll
    for (int j = 0; j < 4; ++j) {
      unsigned w = 0;
#pragma unroll
      for (int i = 0; i < 4; ++i) {
        int iv = (int)rintf(v[j][i] * inv);
        w |= (unsigned)(iv & 0xFF) << (8 * i);
      }
      *(unsigned*)(xq + (size_t)b * KDIM + (tid + 256 * j) * 4) = w;
    }
  }
}

// ---------- kernel 2: 128x128 i8 GEMM, 4 waves, 32KB LDS -> 4 blocks/CU (TLP) ----------
// Register budget: acc 64 AGPR + frags 32 + addr ~20 ≈ 115 total <= 128 = 512/4 waves/SIMD.
// TILEQ sync structure identical to R8/R9 (race-validated): reads ks0(4)+ks1(4) -> BARR
// -> lgkm(4) -> MFMA ks0 -> lgkm(0) -> stage(4) -> MFMA ks1 -> vmcnt(4) -> BARR.
static __device__ __forceinline__ void gload16(const void* g, void* l) {
  __builtin_amdgcn_global_load_lds(
      (const __attribute__((address_space(1))) unsigned*)g,
      (__attribute__((address_space(3))) unsigned*)l, 16, 0, 0);
}

#define BARR() __builtin_amdgcn_s_barrier()
#define LGKM0() asm volatile("s_waitcnt lgkmcnt(0)" ::: "memory")
#define LGKM4() asm volatile("s_waitcnt lgkmcnt(4)" ::: "memory")
#define VMC4() asm volatile("s_waitcnt vmcnt(4)" ::: "memory")
#define SB0() __builtin_amdgcn_sched_barrier(0)

__global__ __launch_bounds__(256, 4) void gemmq3_k(const char* __restrict__ xq,
                                                   const char* __restrict__ wq,
                                                   const float* __restrict__ dxr,
                                                   const float* __restrict__ dwt,
                                                   const float* __restrict__ bias,
                                                   float* __restrict__ out) {
  __shared__ char sA[2 * 128 * 64];  // 16 KiB: [buf][128 rows][64K] i8
  __shared__ char sB[2 * 128 * 64];  // 16 KiB
  const int tid = threadIdx.x;
  const int lane = tid & 63;
  const int wid = tid >> 6;
  const int wm = wid >> 1, wn = wid & 1;  // 2x2 waves, per-wave 64x64 out

  // XCD swizzle with mb-fastest: per XCD, 4 A-panels (2MB) L2-resident and each
  // B-panel reused by 4 consecutive blocks. nwg = 2752 = 8 * 344, 344 = 4mb * 86nb.
  const int bid = blockIdx.x;
  const int mb = 4 * (bid & 7) + ((bid >> 3) & 3);  // 0..31
  const int nb = bid >> 5;                          // 0..85
  const int m0 = mb * 128, n0 = nb * 128;

  // staging: chunk ci in {tid, tid+256}; row = ci>>2 (srow, srow+64), phys pos = tid&3
  const int srow = tid >> 2;  // 0..63
  const int spc = tid & 3;
  const int skb = spc ^ (srow & 3) ^ ((srow >> 2) & 3);  // +64 rows preserves both terms
  const char* gA = xq + (size_t)(m0 + srow) * KDIM + skb * 16;
  const char* gB = wq + (size_t)(n0 + srow) * KDIM + skb * 16;

  auto stA = [&](int b, int kt) {
    gload16(gA + kt * 64, sA + b * 8192 + tid * 16);
    gload16(gA + (size_t)64 * KDIM + kt * 64, sA + b * 8192 + tid * 16 + 4096);
  };
  auto stB = [&](int b, int kt) {
    gload16(gB + kt * 64, sB + b * 8192 + tid * 16);
    gload16(gB + (size_t)64 * KDIM + kt * 64, sB + b * 8192 + tid * 16 + 4096);
  };

  // read addressing: row = wbase + fi*32 + l31 (fi*32 keeps XOR terms), chunk hi5^rsw (^2 for ks1)
  const int l31 = lane & 31, hi5 = lane >> 5;
  const int rsw = (l31 & 3) ^ ((l31 >> 2) & 3);
  const int pc0 = (hi5 ^ rsw) * 16;
  const int pc1 = ((hi5 ^ rsw) ^ 2) * 16;
  const char* aRd = sA + (wm * 64 + l31) * 64;
  const char* bRd = sB + (wn * 64 + l31) * 64;

  int16v acc[2][2];
#pragma unroll
  for (int i = 0; i < 2; ++i)
#pragma unroll
    for (int j = 0; j < 2; ++j) acc[i][j] = (int16v)(0);

#define TILEQ(BUF, TT)                                                        \
  {                                                                           \
    const char* ap = aRd + (BUF) * 8192;                                      \
    const char* bp = bRd + (BUF) * 8192;                                      \
    int4v av[2][2], bv[2][2];                                                 \
    _Pragma("unroll") for (int fi = 0; fi < 2; ++fi)                          \
      av[fi][0] = *(const int4v*)(ap + fi * 2048 + pc0);                      \
    _Pragma("unroll") for (int fj = 0; fj < 2; ++fj)                          \
      bv[fj][0] = *(const int4v*)(bp + fj * 2048 + pc0);                      \
    _Pragma("unroll") for (int fi = 0; fi < 2; ++fi)                          \
      av[fi][1] = *(const int4v*)(ap + fi * 2048 + pc1);                      \
    _Pragma("unroll") for (int fj = 0; fj < 2; ++fj)                          \
      bv[fj][1] = *(const int4v*)(bp + fj * 2048 + pc1);                      \
    SB0();                                                                    \
    BARR();                                                                   \
    LGKM4(); SB0();                                                           \
    __builtin_amdgcn_s_setprio(1);                                            \
    _Pragma("unroll") for (int fi = 0; fi < 2; ++fi)                          \
      _Pragma("unroll") for (int fj = 0; fj < 2; ++fj)                        \
        acc[fi][fj] = __builtin_amdgcn_mfma_i32_32x32x32_i8(av[fi][0], bv[fj][0], acc[fi][fj], 0, 0, 0); \
    __builtin_amdgcn_s_setprio(0);                                            \
    LGKM0(); SB0();                                                           \
    const int kn = ((TT) + 2) & 63;                                           \
    stA(BUF, kn); stB(BUF, kn);                                               \
    SB0();                                                                    \
    __builtin_amdgcn_s_setprio(1);                                            \
    _Pragma("unroll") for (int fi = 0; fi < 2; ++fi)                          \
      _Pragma("unroll") for (int fj = 0; fj < 2; ++fj)                        \
        acc[fi][fj] = __builtin_amdgcn_mfma_i32_32x32x32_i8(av[fi][1], bv[fj][1], acc[fi][fj], 0, 0, 0); \
    __builtin_amdgcn_s_setprio(0);                                            \
    VMC4(); BARR();                                                           \
  }

  // prologue: stage tiles 0,1 (8 loads); vmcnt(4) -> tile0 landed, 4 in flight
  stA(0, 0); stB(0, 0);
  stA(1, 1); stB(1, 1);
  VMC4();
  BARR();

  for (int u = 0; u < 32; ++u) {
    TILEQ(0, 2 * u);
    TILEQ(1, 2 * u + 1);
  }

  // epilogue: C layout (32x32): col = lane&31, row = (e&3) + 8*(e>>2) + 4*(lane>>5)
  const int colb = n0 + wn * 64 + l31;
  const int rowb = m0 + wm * 64 + 4 * hi5;
#pragma unroll
  for (int fi = 0; fi < 2; ++fi) {
#pragma unroll
    for (int fj = 0; fj < 2; ++fj) {
      const int col = colb + fj * 32;
      const float dw = dwt[col];
      const float bs = bias[col];
      int16v c = acc[fi][fj];
#pragma unroll
      for (int e = 0; e < 16; ++e) {
        const int row = rowb + fi * 32 + (e & 3) + 8 * (e >> 2);
        out[(size_t)row * TDIM + col] = (float)c[e] * dw * dxr[row] + bs;
      }
    }
  }
}

extern "C" void kernel_launch(void* const* d_in, const int* in_sizes, int n_in,
                              void* d_out, int out_size, void* d_ws, size_t ws_size,
                              hipStream_t stream) {
  const float* x = (const float*)d_in[0];
  const unsigned* qw = (const unsigned*)d_in[1];
  const float* scales = (const float*)d_in[2];
  const float* zeros = (const float*)d_in[3];
  const float* bias = (const float*)d_in[4];
  float* out = (float*)d_out;

  char* ws = (char*)d_ws;
  char* wq = ws;                                   // [TDIM][KDIM] i8, 45.1MB
  char* xq = ws + (size_t)TDIM * KDIM;             // [BDIM][KDIM] i8, 16.8MB
  float* dwt = (float*)(ws + (size_t)TDIM * KDIM + (size_t)BDIM * KDIM);
  float* dwtinv = dwt + TDIM;
  float* dxr = dwtinv + TDIM;

  dwt_k<<<43, 256, 0, stream>>>(scales, zeros, dwt, dwtinv);
  prep_k<<<9600, 256, 0, stream>>>(qw, scales, zeros, dwtinv, x, wq, xq, dxr);
  gemmq3_k<<<2752, 256, 0, stream>>>(xq, wq, dxr, dwt, bias, out);
}